// Round 10
// baseline (413.718 us; speedup 1.0000x reference)
//
#include <hip/hip_runtime.h>
#include <math.h>

#define TT 8192
#define DZ 32

typedef short bf16x8 __attribute__((ext_vector_type(8)));
typedef _Float16 f16x8 __attribute__((ext_vector_type(8)));
typedef _Float16 f16x4 __attribute__((ext_vector_type(4)));
typedef float f32x4 __attribute__((ext_vector_type(4)));
typedef float f32x16 __attribute__((ext_vector_type(16)));
#define MFMA16F(a,b,c) __builtin_amdgcn_mfma_f32_16x16x32_f16(a,b,c,0,0,0)
#define MFMA32(a,b,c) __builtin_amdgcn_mfma_f32_32x32x16_bf16(a,b,c,0,0,0)

// ---------------- workspace layout (float units) ----------------
#define OFF_QINV   0
#define OFF_Q0INV  1024
#define OFF_AQA    2048
#define OFF_B      3072
#define OFF_P0     4096
#define OFF_PMID   5120
#define OFF_PLAST  6144
#define OFF_LOGSUM 7168
#define OFF_ACT0   8192                     // 2 f16 act slots -> later L (f32, col-major per t)
#define OFF_ACT1   (OFF_ACT0 + 8388608)     // 2 f16 act slots -> later C (f32, X row-major per t)
#define OFF_AAB    (OFF_ACT1 + 8388608)     // cov f32 -> AA in place
#define OFF_XB     (OFF_AAB + 8388608)      // x f16
#define OFF_WB     (OFF_XB + 2097152)       // weights f16
#define OFF_MEANB  (OFF_WB + 5799936)       // meanb; dead after build_blocks -> reused as noise
#define OFF_LAMMU  (OFF_MEANB + 262144)
#define OFF_IBV    (OFF_LAMMU + 262144)

__device__ __forceinline__ unsigned short f2bf(float f) {
    unsigned int u = __float_as_uint(f);
    u += 0x7FFFu + ((u >> 16) & 1u);
    return (unsigned short)(u >> 16);
}
__device__ __forceinline__ float bf2f(unsigned short h) {
    return __uint_as_float(((unsigned int)h) << 16);
}
__device__ __forceinline__ float rlane(float v, int l) {
    return __uint_as_float(__builtin_amdgcn_readlane(__float_as_uint(v), l));
}

// ---------------- fused f32 -> f16 conversion (all tensors, 1 launch) ----------------
struct SplitSeg { const float* src; _Float16* hi; int n; };
struct SplitArgs { SplitSeg seg[9]; };

__global__ __launch_bounds__(256)
void split_all(SplitArgs a)
{
    const SplitSeg sg = a.seg[blockIdx.y];
    const int n4 = sg.n >> 2;
    int i = blockIdx.x * 256 + threadIdx.x;
    if (i >= n4) return;
    float4 v = ((const float4*)sg.src)[i];
    f16x4 hh;
    hh[0] = (_Float16)v.x; hh[1] = (_Float16)v.y;
    hh[2] = (_Float16)v.z; hh[3] = (_Float16)v.w;
    ((f16x4*)sg.hi)[i] = hh;
}

// ---------------- setup: Qinv, Q0inv, AQA, B, priors ----------------
__global__ __launch_bounds__(1024)
void setup_kernel(const float* __restrict__ A, const float* __restrict__ QinvChol,
                  const float* __restrict__ Q0invChol, float* __restrict__ cw)
{
    __shared__ float As[DZ*33], Qc[DZ*33], Q0c[DZ*33], Qi[DZ*33], T1[DZ*33];
    const int tid = threadIdx.x;
    const int i = tid >> 5, j = tid & 31;
    As[i*33+j]  = A[tid];
    Qc[i*33+j]  = QinvChol[tid];
    Q0c[i*33+j] = Q0invChol[tid];
    __syncthreads();
    float qi = 0.f, q0 = 0.f;
    for (int k = 0; k < DZ; ++k) { qi += Qc[i*33+k]*Qc[j*33+k]; q0 += Q0c[i*33+k]*Q0c[j*33+k]; }
    Qi[i*33+j] = qi;
    __syncthreads();
    float t1 = 0.f;
    for (int k = 0; k < DZ; ++k) t1 += Qi[i*33+k]*As[k*33+j];
    T1[i*33+j] = t1;
    __syncthreads();
    float aqa = 0.f, bm = 0.f;
    for (int k = 0; k < DZ; ++k) { aqa += As[k*33+i]*T1[k*33+j]; bm += As[k*33+i]*Qi[k*33+j]; }
    cw[OFF_QINV  + tid] = qi;
    cw[OFF_Q0INV + tid] = q0;
    cw[OFF_AQA   + tid] = aqa;
    cw[OFF_B     + tid] = -bm;
    cw[OFF_P0    + tid] = q0 + aqa;
    cw[OFF_PMID  + tid] = qi + aqa;
    cw[OFF_PLAST + tid] = qi;
    if (tid == 0) cw[OFF_LOGSUM] = 0.f;
}

// ---------------- f16 MFMA GEMM ----------------
__device__ __forceinline__ void stage_tile(const _Float16* src, int rowbase, int Kd,
                                           int k0, _Float16* ldsbase, int w, int lane)
{
#pragma unroll
    for (int inst = 0; inst < 2; ++inst) {
        const int r0  = w * 32 + inst * 16;
        const int row = r0 + (lane >> 2);
        const int g   = (lane & 3) ^ ((row >> 1) & 3);
        const _Float16* gp = src + (size_t)(rowbase + row) * Kd + k0 + g * 8;
        __builtin_amdgcn_global_load_lds(
            (const __attribute__((address_space(1))) void*)gp,
            (__attribute__((address_space(3))) void*)(ldsbase + r0 * 32),
            16, 0, 0);
    }
}

// GEMM body: C = act(A @ W^T + b). OM: 0 f32 out, 1 f16 out.
template<int OM>
__device__ __forceinline__ void mgemm_body(const _Float16* Ah, const _Float16* Wh,
                                           const float* bias, float* outF,
                                           _Float16* outH, int N, int Kd, int relu,
                                           int bn, int bm, _Float16 (*lds)[2][4096])
{
    const int tid = threadIdx.x;
    const int lane = tid & 63, w = tid >> 6;
    const int wm = w >> 1, wn = w & 1;
    const int ln15 = lane & 15, g4 = lane >> 4;

    f32x4 acc[4][4];
#pragma unroll
    for (int i = 0; i < 4; ++i)
#pragma unroll
        for (int j = 0; j < 4; ++j) acc[i][j] = f32x4{0.f,0.f,0.f,0.f};

    const int nt = Kd >> 5;
    stage_tile(Ah, bm*128, Kd, 0, &lds[0][0][0], w, lane);
    stage_tile(Wh, bn*128, Kd, 0, &lds[0][1][0], w, lane);
    __syncthreads();

    int cur = 0;
    for (int t = 0; t < nt; ++t) {
        if (t + 1 < nt) {
            const int k0 = (t + 1) << 5;
            stage_tile(Ah, bm*128, Kd, k0, &lds[cur^1][0][0], w, lane);
            stage_tile(Wh, bn*128, Kd, k0, &lds[cur^1][1][0], w, lane);
        }
        f16x8 fa[4], fwh[4];
#pragma unroll
        for (int fm = 0; fm < 4; ++fm) {
            const int lr = wm*64 + fm*16 + ln15;
            const int off = lr*32 + ((g4 ^ ((lr >> 1) & 3)) << 3);
            fa[fm]  = *(const f16x8*)(&lds[cur][0][0] + off);
        }
#pragma unroll
        for (int fn = 0; fn < 4; ++fn) {
            const int lr = wn*64 + fn*16 + ln15;
            const int off = lr*32 + ((g4 ^ ((lr >> 1) & 3)) << 3);
            fwh[fn] = *(const f16x8*)(&lds[cur][1][0] + off);
        }
#pragma unroll
        for (int fm = 0; fm < 4; ++fm)
#pragma unroll
            for (int fn = 0; fn < 4; ++fn)
                acc[fm][fn] = MFMA16F(fa[fm], fwh[fn], acc[fm][fn]);
        __syncthreads();
        cur ^= 1;
    }

    // epilogue: C/D layout col=lane&15, row=(lane>>4)*4+q  [m89-verified]
#pragma unroll
    for (int fm = 0; fm < 4; ++fm)
#pragma unroll
        for (int fn = 0; fn < 4; ++fn) {
            const int col = bn*128 + wn*64 + fn*16 + ln15;
            const float bv = bias[col];
#pragma unroll
            for (int q = 0; q < 4; ++q) {
                const int row = bm*128 + wm*64 + fm*16 + g4*4 + q;
                float v = acc[fm][fn][q] + bv;
                if (relu) v = fmaxf(v, 0.f);
                if (OM == 0) outF[(size_t)row * N + col] = v;
                else         outH[(size_t)row * N + col] = (_Float16)v;
            }
        }
}

// single-chain GEMM (final cov layer, f32 out)
__global__ __launch_bounds__(256)
void mgemm_f32(const _Float16* __restrict__ Ah, const _Float16* __restrict__ Wh,
               const float* __restrict__ bias, float* __restrict__ outF,
               int N, int Kd)
{
    __shared__ _Float16 lds[2][2][4096];
    mgemm_body<0>(Ah, Wh, bias, outF, nullptr, N, Kd, 0, blockIdx.x, blockIdx.y, lds);
}

// merged mean/cov GEMM: blockIdx.z selects chain (both f16 out, relu)
__global__ __launch_bounds__(256)
void mgemm2(const _Float16* __restrict__ A0, const _Float16* __restrict__ A1,
            const _Float16* __restrict__ W0, const _Float16* __restrict__ W1,
            const float* __restrict__ b0, const float* __restrict__ b1,
            _Float16* __restrict__ o0, _Float16* __restrict__ o1,
            int N, int Kd)
{
    __shared__ _Float16 lds[2][2][4096];
    const int z = blockIdx.z;
    const _Float16* Ah = z ? A1 : A0;
    const _Float16* Wh = z ? W1 : W0;
    const float* bias  = z ? b1 : b0;
    _Float16* outH     = z ? o1 : o0;
    mgemm_body<1>(Ah, Wh, bias, nullptr, outH, N, Kd, 1, blockIdx.x, blockIdx.y, lds);
}

// ---------------- small GEMM (N=32): mean = h3 @ Wm_out^T + b ----------------
__global__ __launch_bounds__(64)
void mgemm_small(const _Float16* __restrict__ Ah, const _Float16* __restrict__ Wh,
                 const float* __restrict__ bias, float* __restrict__ out, int Kd)
{
    const int lane = threadIdx.x;
    const int rm = blockIdx.x * 16;
    const int ln15 = lane & 15, g = lane >> 4;
    const int row = rm + ln15;
    f32x4 acc0 = {0.f,0.f,0.f,0.f}, acc1 = {0.f,0.f,0.f,0.f};
    for (int k0 = 0; k0 < Kd; k0 += 32) {
        const int k = k0 + g*8;
        f16x8 a  = *(const f16x8*)(Ah + (size_t)row*Kd + k);
        f16x8 w0h = *(const f16x8*)(Wh + (size_t)ln15*Kd + k);
        f16x8 w1h = *(const f16x8*)(Wh + (size_t)(16+ln15)*Kd + k);
        acc0 = MFMA16F(a, w0h, acc0);
        acc1 = MFMA16F(a, w1h, acc1);
    }
#pragma unroll
    for (int q = 0; q < 4; ++q) {
        const int r = rm + g*4 + q;
        out[r*DZ + ln15]      = acc0[q] + bias[ln15];
        out[r*DZ + 16 + ln15] = acc1[q] + bias[16 + ln15];
    }
}

// ---------------- build Lam, AA (in place over cov), lamMu ----------------
__global__ __launch_bounds__(256)
void build_blocks_kernel(float* __restrict__ cov, const float* __restrict__ mean,
                         float* __restrict__ lamMu, const float* __restrict__ cw)
{
    const int t = blockIdx.x, tid = threadIdx.x;
    __shared__ float R[DZ*33];
    __shared__ float Lam[DZ*33];
    __shared__ float mn[DZ];
    float* blk = cov + (size_t)t * 1024;
    {
        float4 v = ((const float4*)blk)[tid];
        const int base = tid * 4;
        const int row = base >> 5, col = base & 31;
        R[row*33 + col + 0] = v.x; R[row*33 + col + 1] = v.y;
        R[row*33 + col + 2] = v.z; R[row*33 + col + 3] = v.w;
    }
    if (tid < DZ) mn[tid] = mean[t*DZ + tid];
    __syncthreads();
    const float* P = cw + (t == 0 ? OFF_P0 : (t == TT-1 ? OFF_PLAST : OFF_PMID));
#pragma unroll
    for (int q = 0; q < 4; ++q) {
        const int idx = tid + 256*q;
        const int i = idx >> 5, j = idx & 31;
        float s = 0.f;
#pragma unroll
        for (int k = 0; k < DZ; ++k) s += R[i*33+k] * R[j*33+k];
        Lam[i*33+j] = s;
        blk[idx] = s + P[idx];
    }
    __syncthreads();
    if (tid < DZ) {
        float s = 0.f;
#pragma unroll
        for (int k = 0; k < DZ; ++k) s += Lam[tid*33+k] * mn[k];
        lamMu[t*DZ + tid] = s;
    }
}

// ---------------- chol scan v7: batched readlanes (SGPR-hazard removal) ----------
__device__ __forceinline__ unsigned short f2bf_c(float f) { return f2bf(f); }

#define CHOL_STEP(OWNED)                                                          \
    {                                                                             \
        _Pragma("unroll")                                                         \
        for (int i = 0; i < 32; ++i) s[i] = Apre[i];                              \
        if (t + 1 < own1) {                                                       \
            const float* an = AA + (size_t)(t+1)*1024;                            \
            _Pragma("unroll")                                                     \
            for (int i = 0; i < 32; ++i) Apre[i] = an[i*32 + c];                  \
        }                                                                         \
        const bool doX = (t > t0);                                                \
        if (doX) {                                                                \
            _Pragma("unroll")                                                     \
            for (int i = 0; i < 32; ++i) u[i] = Breg[i];                          \
            _Pragma("unroll")                                                     \
            for (int r = 0; r < 32; ++r) {                                        \
                float x = u[r] * rlane(invd_own, r);                              \
                u[r] = x;                                                         \
                float mm[32];                                                     \
                _Pragma("unroll")                                                 \
                for (int i = r+1; i < 32; ++i) mm[i] = rlane(Lcol[i], r);         \
                _Pragma("unroll")                                                 \
                for (int i = r+1; i < 32; ++i) u[i] = fmaf(-mm[i], x, u[i]);      \
            }                                                                     \
            float f0[8], f1[8];                                                   \
            _Pragma("unroll")                                                     \
            for (int j = 0; j < 8; ++j) {                                         \
                f0[j] = h ? u[8+j]  : u[j];                                       \
                f1[j] = h ? u[24+j] : u[16+j];                                    \
            }                                                                     \
            bf16x8 A0h, A0l, A1h, A1l;                                            \
            _Pragma("unroll")                                                     \
            for (int j = 0; j < 8; ++j) {                                         \
                unsigned short hh0 = f2bf_c(f0[j]);                               \
                A0h[j] = (short)hh0; A0l[j] = (short)f2bf_c(f0[j] - bf2f(hh0));   \
                unsigned short hh1 = f2bf_c(f1[j]);                               \
                A1h[j] = (short)hh1; A1l[j] = (short)f2bf_c(f1[j] - bf2f(hh1));   \
            }                                                                     \
            f32x16 d;                                                             \
            _Pragma("unroll")                                                     \
            for (int q = 0; q < 16; ++q) d[q] = 0.f;                              \
            d = MFMA32(A0h, A0h, d);                                              \
            d = MFMA32(A0h, A0l, d);                                              \
            d = MFMA32(A0l, A0h, d);                                              \
            d = MFMA32(A1h, A1h, d);                                              \
            d = MFMA32(A1h, A1l, d);                                              \
            d = MFMA32(A1l, A1h, d);                                              \
            float dsw[16];                                                        \
            _Pragma("unroll")                                                     \
            for (int q = 0; q < 16; ++q) dsw[q] = __shfl_xor(d[q], 32);           \
            _Pragma("unroll")                                                     \
            for (int i = 0; i < 32; ++i) {                                        \
                const int q  = (i & 3) + ((i >> 3) << 2);                         \
                const int hh = (i >> 2) & 1;                                      \
                s[i] -= (h == hh) ? d[q] : dsw[q];                                \
            }                                                                     \
        }                                                                         \
        float pivk = 1.f;                                                         \
        _Pragma("unroll")                                                         \
        for (int j = 0; j < 32; ++j) {                                            \
            float sjj = rlane(s[j], j);                                           \
            float inv = __builtin_amdgcn_rsqf(sjj);                               \
            pivk = (c == j) ? sjj : pivk;                                         \
            float inv2 = inv * inv;                                               \
            float ljc = (c > j) ? s[j] * inv2 : 0.f;                              \
            invd_own = (c == j) ? inv : invd_own;                                 \
            float mm[32];                                                         \
            _Pragma("unroll")                                                     \
            for (int i = j; i < 32; ++i) mm[i] = rlane(s[i], j);                  \
            _Pragma("unroll")                                                     \
            for (int i = j; i < 32; ++i) s[i] = fmaf(-mm[i], ljc, s[i]);          \
        }                                                                         \
        if (OWNED) logacc += __logf(pivk);                                        \
        _Pragma("unroll")                                                         \
        for (int i = 0; i < 32; ++i) Lcol[i] = s[i] * invd_own;                   \
        if (OWNED) {                                                              \
            float* lt = Lg + (size_t)t*1024 + c*32 + h*16;                        \
            _Pragma("unroll")                                                     \
            for (int q = 0; q < 4; ++q) {                                         \
                float4 v4 = make_float4(h ? Lcol[16+4*q]   : Lcol[4*q],           \
                                        h ? Lcol[16+4*q+1] : Lcol[4*q+1],         \
                                        h ? Lcol[16+4*q+2] : Lcol[4*q+2],         \
                                        h ? Lcol[16+4*q+3] : Lcol[4*q+3]);        \
                *(float4*)(lt + 4*q) = v4;                                        \
            }                                                                     \
            if (doX) {                                                            \
                float* ct = Cg + (size_t)t*1024;                                  \
                _Pragma("unroll")                                                 \
                for (int rr = 0; rr < 16; ++rr) {                                 \
                    float val = h ? u[16+rr] : u[rr];                             \
                    ct[(h*16+rr)*32 + c] = val;                                   \
                }                                                                 \
            }                                                                     \
        }                                                                         \
    }

__global__ __launch_bounds__(64)
void chol_scan7(const float* __restrict__ AA, float* __restrict__ Lg,
                float* __restrict__ Cg, const float* __restrict__ cw,
                float* __restrict__ logsum, int K, int W)
{
    const int lane = threadIdx.x;
    const int c = lane & 31;
    const int h = lane >> 5;
    const int own0 = blockIdx.x * K;
    const int own1 = min(TT, own0 + K);
    const int t0 = max(0, own0 - W);

    float Breg[32], Lcol[32], s[32], u[32], Apre[32];
    float invd_own = 0.f, logacc = 0.f;

#pragma unroll
    for (int i = 0; i < 32; ++i) Breg[i] = cw[OFF_B + i*32 + c];
#pragma unroll
    for (int i = 0; i < 32; ++i) Apre[i] = AA[(size_t)t0*1024 + i*32 + c];

    for (int t = t0; t < own0; ++t) CHOL_STEP(false)
    for (int t = own0; t < own1; ++t) CHOL_STEP(true)

    // lane c holds sum over owned steps of log(pivot_c); butterfly within 32
#pragma unroll
    for (int sft = 16; sft > 0; sft >>= 1) logacc += __shfl_xor(logacc, sft);
    if (lane == 0) atomicAdd(logsum, logacc * 0.5f);
}

// ---------------- solve pair: y=0 fwd (lamMu->ib), y=1 bwd single-RHS (norm->noise) ----
__global__ __launch_bounds__(64)
void solve_pair_kernel(const float* __restrict__ Lg, const float* __restrict__ Cg,
                       const float* __restrict__ bF, const float* __restrict__ bB,
                       float* __restrict__ ib, float* __restrict__ noise,
                       int K, int W)
{
    const int lane = threadIdx.x;
    const int own0 = blockIdx.x * K;
    const int own1 = min(TT, own0 + K);

    if (blockIdx.y == 0) {
        // forward: x_t = L_t^{-1}(b_t - C_t x_{t-1})
        const int r = lane & 31, h = lane >> 5;
        const int t0 = max(0, own0 - W);
        float xprev = 0.f;
        for (int t = t0; t < own1; ++t) {
            const float* lt = Lg + (size_t)t * 1024;
            float Lr[32];
#pragma unroll
            for (int j = 0; j < DZ; ++j) Lr[j] = lt[j*32 + r];
            const float inv = __builtin_amdgcn_rcpf(Lr[r]);
            float v = bF[t*DZ + r];
            if (t > t0) {
                const float* ct = Cg + (size_t)t * 1024;
                float Cr[32];
#pragma unroll
                for (int cc = 0; cc < DZ; ++cc) Cr[cc] = ct[cc*32 + r];
#pragma unroll
                for (int cc = 0; cc < DZ; ++cc) v = fmaf(-Cr[cc], __shfl(xprev, cc), v);
            }
            float xv = 0.f;
#pragma unroll
            for (int rr = 0; rr < DZ; ++rr) {
                float cand = v * inv;
                float xb = __shfl(cand, rr);
                if (r == rr) xv = cand;
                if (r > rr) v = fmaf(-Lr[rr], xb, v);
            }
            xprev = xv;
            if (t >= own0 && h == 0) ib[t*DZ + r] = xv;
        }
    } else {
        // backward single RHS: x_t = L_t^{-T}(b_t - C_{t+1}^T x_{t+1})
        const int k = lane & 31, h = lane >> 5;
        const int tS = min(TT - 1, own1 - 1 + W);
        float x1p = 0.f;
        for (int t = tS; t >= own0; --t) {
            const float* lt = Lg + (size_t)t * 1024;
            float Lc[32];
#pragma unroll
            for (int q = 0; q < 8; ++q) {
                float4 v4 = *(const float4*)(lt + k*32 + 4*q);
                Lc[4*q] = v4.x; Lc[4*q+1] = v4.y; Lc[4*q+2] = v4.z; Lc[4*q+3] = v4.w;
            }
            const float inv = __builtin_amdgcn_rcpf(Lc[k]);
            float v1 = bB[t*DZ + k];
            if (t < tS) {
                const float* ct = Cg + (size_t)(t+1) * 1024;
                float Cc[32];
#pragma unroll
                for (int q = 0; q < 8; ++q) {
                    float4 w4 = *(const float4*)(ct + k*32 + 4*q);
                    Cc[4*q] = w4.x; Cc[4*q+1] = w4.y; Cc[4*q+2] = w4.z; Cc[4*q+3] = w4.w;
                }
#pragma unroll
                for (int cc = 0; cc < DZ; ++cc) v1 = fmaf(-Cc[cc], __shfl(x1p, cc), v1);
            }
            float x1 = 0.f;
#pragma unroll
            for (int rr = DZ-1; rr >= 0; --rr) {
                float c1 = v1 * inv;
                float xb1 = __shfl(c1, rr);
                if (k == rr) x1 = c1;
                if (k < rr) v1 = fmaf(-Lc[rr], xb1, v1);
            }
            x1p = x1;
            if (t >= own0 && h == 0) noise[t*DZ + k] = x1;
        }
    }
}

// ---------------- final backward solve over ib, add noise, write sample --------------
__global__ __launch_bounds__(64)
void bwd_final_kernel(const float* __restrict__ Lg, const float* __restrict__ Cg,
                      const float* __restrict__ b1, const float* __restrict__ noise,
                      float* __restrict__ outSample, int K, int W)
{
    const int lane = threadIdx.x;
    const int k = lane & 31, h = lane >> 5;
    const int own0 = blockIdx.x * K;
    const int own1 = min(TT, own0 + K);
    const int tS = min(TT - 1, own1 - 1 + W);
    float x1p = 0.f;
    for (int t = tS; t >= own0; --t) {
        const float* lt = Lg + (size_t)t * 1024;
        float Lc[32];
#pragma unroll
        for (int q = 0; q < 8; ++q) {
            float4 v4 = *(const float4*)(lt + k*32 + 4*q);
            Lc[4*q] = v4.x; Lc[4*q+1] = v4.y; Lc[4*q+2] = v4.z; Lc[4*q+3] = v4.w;
        }
        const float inv = __builtin_amdgcn_rcpf(Lc[k]);
        float v1 = b1[t*DZ + k];
        if (t < tS) {
            const float* ct = Cg + (size_t)(t+1) * 1024;
            float Cc[32];
#pragma unroll
            for (int q = 0; q < 8; ++q) {
                float4 w4 = *(const float4*)(ct + k*32 + 4*q);
                Cc[4*q] = w4.x; Cc[4*q+1] = w4.y; Cc[4*q+2] = w4.z; Cc[4*q+3] = w4.w;
            }
#pragma unroll
            for (int cc = 0; cc < DZ; ++cc) v1 = fmaf(-Cc[cc], __shfl(x1p, cc), v1);
        }
        float x1 = 0.f;
#pragma unroll
        for (int rr = DZ-1; rr >= 0; --rr) {
            float c1 = v1 * inv;
            float xb1 = __shfl(c1, rr);
            if (k == rr) x1 = c1;
            if (k < rr) v1 = fmaf(-Lc[rr], xb1, v1);
        }
        x1p = x1;
        if (t >= own0 && h == 0) outSample[t*DZ + k] = x1 + noise[t*DZ + k];
    }
}

// ---------------- entropy ----------------
__global__ void finalize_kernel(const float* __restrict__ logsum, float* __restrict__ out)
{
    if (threadIdx.x == 0) {
        out[TT*DZ] = (logsum[0] - 2270.3016531274763f) / 409600.0f;
    }
}

// ---------------- launch ----------------
extern "C" void kernel_launch(void* const* d_in, const int* in_sizes, int n_in,
                              void* d_out, int out_size, void* d_ws, size_t ws_size,
                              hipStream_t stream)
{
    (void)in_sizes; (void)n_in; (void)out_size; (void)ws_size;
    const float* x        = (const float*)d_in[0];
    const float* norm     = (const float*)d_in[1];
    const float* A        = (const float*)d_in[2];
    const float* QinvChol = (const float*)d_in[3];
    const float* Q0invChol= (const float*)d_in[4];
    const float* Wm_in = (const float*)d_in[5];  const float* bm_in = (const float*)d_in[6];
    const float* Wm_h1 = (const float*)d_in[7];  const float* bm_h1 = (const float*)d_in[8];
    const float* Wm_h3 = (const float*)d_in[9];  const float* bm_h3 = (const float*)d_in[10];
    const float* Wm_out= (const float*)d_in[11]; const float* bm_out= (const float*)d_in[12];
    const float* Wc_in = (const float*)d_in[13]; const float* bc_in = (const float*)d_in[14];
    const float* Wc_h1 = (const float*)d_in[15]; const float* bc_h1 = (const float*)d_in[16];
    const float* Wc_h3 = (const float*)d_in[17]; const float* bc_h3 = (const float*)d_in[18];
    const float* Wc_out= (const float*)d_in[19]; const float* bc_out= (const float*)d_in[20];

    float* ws    = (float*)d_ws;
    float* out   = (float*)d_out;
    float* cw    = ws;
    float* Lbuf  = ws + OFF_ACT0;
    float* Cbuf  = ws + OFF_ACT1;
    float* covb  = ws + OFF_AAB;
    float* meanb = ws + OFF_MEANB;   // reused as noise after build_blocks
    float* lamMu = ws + OFF_LAMMU;
    float* ib    = ws + OFF_IBV;
    float* logsum = ws + OFF_LOGSUM;
    float* noise = ws + OFF_MEANB;

    // 4 f16 activation slots, carved from ACT0/ACT1 regions
    _Float16* s0 = (_Float16*)(ws + OFF_ACT0);
    _Float16* s1 = s0 + 8388608;
    _Float16* s2 = (_Float16*)(ws + OFF_ACT1);
    _Float16* s3 = s2 + 8388608;
    _Float16* xh = (_Float16*)(ws + OFF_XB);

    const long OWmi = OFF_WB;
    const long OWm1 = OWmi + 262144;
    const long OWm3 = OWm1 + 1048576;
    const long OWmo = OWm3 + 1048576;
    const long OWci = OWmo + 32768;
    const long OWc1 = OWci + 262144;
    const long OWc3 = OWc1 + 1048576;
    const long OWco = OWc3 + 1048576;
    #define WH(o) ((_Float16*)(ws + (o)))

    setup_kernel<<<dim3(1), dim3(1024), 0, stream>>>(A, QinvChol, Q0invChol, cw);

    SplitArgs sa;
    sa.seg[0] = { x,      xh,       2097152 };
    sa.seg[1] = { Wm_in,  WH(OWmi), 262144 };
    sa.seg[2] = { Wm_h1,  WH(OWm1), 1048576 };
    sa.seg[3] = { Wm_h3,  WH(OWm3), 1048576 };
    sa.seg[4] = { Wm_out, WH(OWmo), 32768 };
    sa.seg[5] = { Wc_in,  WH(OWci), 262144 };
    sa.seg[6] = { Wc_h1,  WH(OWc1), 1048576 };
    sa.seg[7] = { Wc_h3,  WH(OWc3), 1048576 };
    sa.seg[8] = { Wc_out, WH(OWco), 1048576 };
    split_all<<<dim3(2048, 9), dim3(256), 0, stream>>>(sa);

    const dim3 gM(8, 64, 2), blk(256);
    // L1: x -> s0 (mean h1) / s1 (cov h1)
    mgemm2<<<gM, blk, 0, stream>>>(xh, xh, WH(OWmi), WH(OWci), bm_in, bc_in, s0, s1, 1024, 256);
    // L2: s0 -> s2 / s1 -> s3
    mgemm2<<<gM, blk, 0, stream>>>(s0, s1, WH(OWm1), WH(OWc1), bm_h1, bc_h1, s2, s3, 1024, 1024);
    // L3: s2 -> s0 / s3 -> s1
    mgemm2<<<gM, blk, 0, stream>>>(s2, s3, WH(OWm3), WH(OWc3), bm_h3, bc_h3, s0, s1, 1024, 1024);
    // heads
    mgemm_small<<<dim3(512), dim3(64), 0, stream>>>(s0, WH(OWmo), bm_out, meanb, 1024);
    mgemm_f32<<<dim3(8, 64), blk, 0, stream>>>(s1, WH(OWco), bc_out, covb, 1024, 1024);

    build_blocks_kernel<<<dim3(TT), dim3(256), 0, stream>>>(covb, meanb, lamMu, cw);

    chol_scan7<<<dim3(TT/4), dim3(64), 0, stream>>>(covb, Lbuf, Cbuf, cw, logsum, 4, 3);
    // fwd (lamMu->ib) runs concurrently with bwd-noise (norm->noise); both only need L,C
    solve_pair_kernel<<<dim3(TT/4, 2), dim3(64), 0, stream>>>(Lbuf, Cbuf, lamMu, norm, ib, noise, 4, 6);
    bwd_final_kernel<<<dim3(TT/4), dim3(64), 0, stream>>>(Lbuf, Cbuf, ib, noise, out, 4, 6);

    finalize_kernel<<<dim3(1), dim3(64), 0, stream>>>(logsum, out);
}